// Round 9
// baseline (3493.857 us; speedup 1.0000x reference)
//
#include <hip/hip_runtime.h>

typedef unsigned short u16;
typedef unsigned int   u32;
typedef unsigned long long u64;

#define B_    8
#define N_    8192
#define CIN   64
#define COUT  128
#define NS    2048
#define K_    32
#define LDSPAD 136   // 128 + 8 bf16: breaks bank conflicts on column stride

typedef __attribute__((ext_vector_type(8))) short short8;
typedef __attribute__((ext_vector_type(4))) float f32x4;
typedef __attribute__((ext_vector_type(2))) float f32x2;

#define MFMA16(a,b,c) __builtin_amdgcn_mfma_f32_16x16x32_bf16(a,b,c,0,0,0)

__device__ __forceinline__ u16 f2bf(float f){
  u32 u = __float_as_uint(f);
  return (u16)((u + 0x7FFFu + ((u >> 16) & 1u)) >> 16);   // RNE, finite values only
}
__device__ __forceinline__ float bf2f(u16 h){ u32 u = ((u32)h) << 16; return __uint_as_float(u); }
__device__ __forceinline__ u32 pack2bf(float lo, float hi){ return (u32)f2bf(lo) | ((u32)f2bf(hi) << 16); }

// fps_idx -> -1 sentinel, done/wready -> 0 (per launch; graph replay reuses ws)
__global__ void clear_kernel(int* __restrict__ fps_idx, u32* __restrict__ done,
                             u32* __restrict__ wready){
  int i = blockIdx.x * 256 + threadIdx.x;
  if (i < B_*NS){ fps_idx[i] = -1; done[i] = 0u; }
  if (i == 0) wready[0] = 0u;
}

struct BnPtrs { const float* g[9]; const float* b[9]; const float* m[9]; const float* v[9]; };

// ---------------------------------------------------------------------------
// MEGA-KERNEL round-9.
// Null-probe tally on fps (~2600 cyc/step floor): instruction cuts, LDS->reg,
// 3 combine structures, barrier semantics, publish batching, wave topology —
// all +-10%. Remaining standalone->mega gap (1.08 -> 1.32 us/step) matches a
// DVFS clock ratio. Round-9: PERSISTENT CAPPED CONSUMERS — 96 knn+mid blocks
// + 16 pos blocks loop over work units (same interleaved mapping; block ib
// walks ib, ib+96, ... = same batch, forward in stream) -> grid 121 blocks,
// 135 CUs fully idle -> less chip power (no spin herd) -> clock headroom for
// the 8 fps CUs. Consumer capacity margin ~15x. fps reverted to best-measured
// v9 (r6: reg points, 8 waves, tree combine, lgkm-only barrier).
//   blocks 0..7    : fps (one batch each; 82KB union -> 1 block/CU)
//   block  8       : prep (weight cvt + bn constants, write-through)
//   blocks 9..104  : knn+mid persistent (96 blocks x ~21 units of 8 centers)
//   blocks 105..120: pos persistent (16 blocks x 4 units of 8 col-groups)
// ---------------------------------------------------------------------------
struct ShFps {
  __align__(16) u64  keyA[2][8];
  __align__(16) f32x4 cA[2][8];
};
struct ShMid {
  __align__(16) u16 X[8][32*LDSPAD];
  __align__(16) float scr[8][128];
};
struct ShPos {
  __align__(16) u16 X[8][32*LDSPAD];
};
union ShAll { ShFps f; ShMid m; ShPos p; char pad[83968]; };  // 82KB -> 1 blk/CU

// loop barrier WITHOUT vmem drain: only LDS ordering is needed inside the fps
// loop (publish stores are fire-and-forget relaxed atomics). sched_barrier
// fences prevent hipcc from hoisting ops across the asm (guide rule 18).
__device__ __forceinline__ void lds_barrier(){
  __builtin_amdgcn_sched_barrier(0);
  asm volatile("s_waitcnt lgkmcnt(0)\n\ts_barrier" ::: "memory");
  __builtin_amdgcn_sched_barrier(0);
}

// ---------------------------------------------------------------------------
// FPS v9 core (r6 best: 2711us in-mega). Exact f32 (contract off); tie ->
// lowest index (bit-identical selection to v5 at every step).
// ---------------------------------------------------------------------------
#define DPP_UMAX(x, ctrl) { \
  u32 o = (u32)__builtin_amdgcn_update_dpp((int)(x), (int)(x), ctrl, 0xf, 0xf, false); \
  x = (o > x) ? o : x; }

__device__ __forceinline__ u32 wave_umax63(u32 x){
  DPP_UMAX(x, 0x111)  // row_shr:1
  DPP_UMAX(x, 0x112)  // row_shr:2
  DPP_UMAX(x, 0x114)  // row_shr:4
  DPP_UMAX(x, 0x118)  // row_shr:8
  DPP_UMAX(x, 0x142)  // row_bcast:15
  DPP_UMAX(x, 0x143)  // row_bcast:31
  return (u32)__builtin_amdgcn_readlane((int)x, 63);
}

// pair m covers points base+2m, base+2m+1. Packed distance update:
// dd = (dx*dx + dy*dy) + dz*dz elementwise == scalar assoc of np.sum axis=-1.
#define FPS_PAIR(m) { \
  f32x2 dx = PXr##m - lx2; \
  f32x2 dy = PYr##m - ly2; \
  f32x2 dz = PZr##m - lz2; \
  f32x2 t0 = dx*dx; \
  f32x2 t1 = dy*dy; \
  f32x2 t2 = dz*dz; \
  f32x2 dd = (t0 + t1) + t2; \
  f32x2 nd; \
  nd.x = fminf(Dr##m.x, dd.x); \
  nd.y = fminf(Dr##m.y, dd.y); \
  Dr##m = nd; \
  fmA = fmaxf(fmA, nd.x); \
  fmB = fmaxf(fmB, nd.y); }

// descending order: last matching assignment wins -> lowest k (exact ties).
// Winner coords selected from THIS lane's registers (no LDS round-trip).
#define FPS_SELK(m) { \
  if (Dr##m.y == wmf){ kk = 2*m + 1; wx = PXr##m.y; wy = PYr##m.y; wz = PZr##m.y; } \
  if (Dr##m.x == wmf){ kk = 2*m;     wx = PXr##m.x; wy = PYr##m.x; wz = PZr##m.x; } }

__device__ __forceinline__ void selmax(u64& ka, f32x4& ca, u64 kb, f32x4 cb){
  bool c = kb > ka;
  ka = c ? kb : ka;
  ca = c ? cb : ca;
}

__device__ void fps_path(const float* __restrict__ xyz, int* __restrict__ fps_idx,
                         ShFps& S, int b, int t){
  #pragma clang fp contract(off)
  const int lane = t & 63, wv = t >> 6;
  const float* xb = xyz + (size_t)b * N_ * 3;
  const int base = t * 16;
  // global -> registers: this thread's 16 points are bytes [base*12, +192),
  // contiguous and 16B-aligned -> 12 coalesced f32x4 loads.
  f32x4 raw0, raw1, raw2, raw3, raw4, raw5, raw6, raw7, raw8, raw9, rawA, rawB;
  {
    const f32x4* xv = (const f32x4*)(xb + (size_t)base * 3);
    raw0 = xv[0]; raw1 = xv[1]; raw2 = xv[2];  raw3 = xv[3];
    raw4 = xv[4]; raw5 = xv[5]; raw6 = xv[6];  raw7 = xv[7];
    raw8 = xv[8]; raw9 = xv[9]; rawA = xv[10]; rawB = xv[11];
  }
  // unpack [x0 y0 z0 x1 y1 z1 ...] into coord pairs (all static indices)
  f32x2 PXr0,PXr1,PXr2,PXr3,PXr4,PXr5,PXr6,PXr7;
  f32x2 PYr0,PYr1,PYr2,PYr3,PYr4,PYr5,PYr6,PYr7;
  f32x2 PZr0,PZr1,PZr2,PZr3,PZr4,PZr5,PZr6,PZr7;
  #define GETF(k) (k<4?raw0[(k)&3]:k<8?raw1[(k)&3]:k<12?raw2[(k)&3]:k<16?raw3[(k)&3]: \
                   k<20?raw4[(k)&3]:k<24?raw5[(k)&3]:k<28?raw6[(k)&3]:k<32?raw7[(k)&3]: \
                   k<36?raw8[(k)&3]:k<40?raw9[(k)&3]:k<44?rawA[(k)&3]:rawB[(k)&3])
  #define SETP(m) { \
    PXr##m.x = GETF(6*m+0); PXr##m.y = GETF(6*m+3); \
    PYr##m.x = GETF(6*m+1); PYr##m.y = GETF(6*m+4); \
    PZr##m.x = GETF(6*m+2); PZr##m.y = GETF(6*m+5); }
  SETP(0) SETP(1) SETP(2) SETP(3) SETP(4) SETP(5) SETP(6) SETP(7)
  #undef SETP
  #undef GETF
  if (t == 0)
    __hip_atomic_store(fps_idx + b*NS, 0, __ATOMIC_RELAXED, __HIP_MEMORY_SCOPE_AGENT);
  f32x2 Dr0,Dr1,Dr2,Dr3,Dr4,Dr5,Dr6,Dr7;
  Dr0=Dr1=Dr2=Dr3=Dr4=Dr5=Dr6=Dr7=(f32x2){1e10f,1e10f};
  const float sx = xb[0], sy = xb[1], sz = xb[2];   // point 0 is the seed
  f32x2 lx2 = {sx,sx}, ly2 = {sy,sy}, lz2 = {sz,sz};
  int my_pi = 0;                                // batched-publish register slot
  for (int s = 0; s < NS - 1; ++s){
    float fmA = 0.f, fmB = 0.f;                 // dists >= 0
    FPS_PAIR(0) FPS_PAIR(1) FPS_PAIR(2) FPS_PAIR(3)
    FPS_PAIR(4) FPS_PAIR(5) FPS_PAIR(6) FPS_PAIR(7)
    const float fm = fmaxf(fmA, fmB);
    const u32 tbm = __float_as_uint(fm);        // >=0 -> bit-max == f32-max
    const u32 wmax = wave_umax63(tbm);          // 6 VALU DPP ops + readlane
    const u64 mask = __ballot(tbm == wmax);
    const int fl = __ffsll((long long)mask) - 1;   // lowest lane = lowest index
    const int sl = s & 1;
    if (lane == fl){
      const float wmf = __uint_as_float(wmax);  // dists +0-or-positive:
      int kk = 0;                               // f32 eq == bit eq here
      float wx = PXr0.x, wy = PYr0.x, wz = PZr0.x;
      FPS_SELK(7) FPS_SELK(6) FPS_SELK(5) FPS_SELK(4)
      FPS_SELK(3) FPS_SELK(2) FPS_SELK(1) FPS_SELK(0)
      const int pi = base + kk;                  // first max index in this wave
      S.keyA[sl][wv] = ((u64)wmax << 13) | (u64)(8191 - pi);
      f32x4 c; c[0] = wx; c[1] = wy; c[2] = wz; c[3] = 0.f;
      S.cA[sl][wv] = c;
    }
    lds_barrier();                              // records visible; no vm drain
    // all threads: 16 broadcast reads + depth-3 tree select over UNIQUE keys
    u64 k0 = S.keyA[sl][0], k1 = S.keyA[sl][1], k2 = S.keyA[sl][2], k3 = S.keyA[sl][3];
    u64 k4 = S.keyA[sl][4], k5 = S.keyA[sl][5], k6 = S.keyA[sl][6], k7 = S.keyA[sl][7];
    f32x4 c0 = S.cA[sl][0], c1 = S.cA[sl][1], c2 = S.cA[sl][2], c3 = S.cA[sl][3];
    f32x4 c4 = S.cA[sl][4], c5 = S.cA[sl][5], c6 = S.cA[sl][6], c7 = S.cA[sl][7];
    selmax(k0,c0,k1,c1); selmax(k2,c2,k3,c3); selmax(k4,c4,k5,c5); selmax(k6,c6,k7,c7);
    selmax(k0,c0,k2,c2); selmax(k4,c4,k6,c6);
    selmax(k0,c0,k4,c4);
    lx2.x = c0[0]; lx2.y = c0[0];
    ly2.x = c0[1]; ly2.y = c0[1];
    lz2.x = c0[2]; lz2.y = c0[2];
    // batched publish (16): step s fills lane (s&15); at s&15==15 wave-0
    // lanes 0..15 store slots s-14..s+1 (relaxed agent; never drained in-loop)
    const int pi_out = 8191 - (int)(k0 & 0x1FFFull);
    if (lane == (s & 15)) my_pi = pi_out;
    if ((s & 15) == 15 && t < 16)
      __hip_atomic_store(fps_idx + b*NS + s - 14 + t, my_pi,
                         __ATOMIC_RELAXED, __HIP_MEMORY_SCOPE_AGENT);
  }
  // steps 2032..2046 filled lanes 0..14 -> slots 2033..2047
  if (t < 15)
    __hip_atomic_store(fps_idx + b*NS + (NS - 15) + t, my_pi,
                       __ATOMIC_RELAXED, __HIP_MEMORY_SCOPE_AGENT);
}

// ---------------------------------------------------------------------------
// prep: weight f32->bf16 + bn constants, all via WRITE-THROUGH relaxed-atomic
// u32 stores (visible at L3 coherence point; consumers first-touch-read after
// the wready gate). One 512-thread block, ~10us.
// ---------------------------------------------------------------------------
__device__ __forceinline__ void st_wt(u32* p, u32 v){
  __hip_atomic_store(p, v, __ATOMIC_RELAXED, __HIP_MEMORY_SCOPE_AGENT);
}

__device__ void prep_path(const float* s_te, const float* s_pre1, const float* s_pre2,
    const float* s_pos1, const float* s_pos2,
    u16* te_w, u16* pre_w1, u16* pre_w2, u16* pos_w1, u16* pos_w2,
    BnPtrs bp, float* bns, u32* wready, int t){
  #define CVT2(src, dst, n) \
    for (int i = t; i < (n)/2; i += 512) \
      st_wt((u32*)(dst) + i, pack2bf((src)[2*i], (src)[2*i+1]));
  CVT2(s_te,   te_w,   16384)
  CVT2(s_pre1, pre_w1, 32768)
  CVT2(s_pre2, pre_w2, 32768)
  CVT2(s_pos1, pos_w1, 32768)
  CVT2(s_pos2, pos_w2, 32768)
  #undef CVT2
  for (int i = t; i < 9*128; i += 512){
    int set = i >> 7, c = i & 127;
    float sc = bp.g[set][c] / sqrtf(bp.v[set][c] + 1e-5f);
    st_wt((u32*)(bns + set*256 + c),       __float_as_uint(sc));
    st_wt((u32*)(bns + set*256 + 128 + c), __float_as_uint(bp.b[set][c] - bp.m[set][c] * sc));
  }
  __syncthreads();   // per-wave vmcnt(0) drain of all the stores above
  if (t == 0)
    __hip_atomic_store(wready, 1u, __ATOMIC_RELEASE, __HIP_MEMORY_SCOPE_AGENT);
}

// ---------------------------------------------------------------------------
// Conv stack helpers (unchanged, m89-verified MFMA layouts).
// ---------------------------------------------------------------------------
__device__ __forceinline__ void zero_acc(f32x4 acc[8][2]){
  #pragma unroll
  for (int mt = 0; mt < 8; ++mt)
    #pragma unroll
    for (int nt = 0; nt < 2; ++nt){
      acc[mt][nt][0] = 0.f; acc[mt][nt][1] = 0.f; acc[mt][nt][2] = 0.f; acc[mt][nt][3] = 0.f;
    }
}

__device__ __forceinline__ void conv_step(const u16* __restrict__ W, const u16* __restrict__ Xw,
                                          int q, int l15, f32x4 acc[8][2]){
  #pragma unroll
  for (int kk = 0; kk < 4; ++kk){
    short8 b0 = *(const short8*)(Xw + l15*LDSPAD + kk*32 + q*8);
    short8 b1 = *(const short8*)(Xw + (16 + l15)*LDSPAD + kk*32 + q*8);
    #pragma unroll
    for (int mt = 0; mt < 8; ++mt){
      short8 a = *(const short8*)(W + (size_t)(mt*16 + l15)*COUT + kk*32 + q*8);
      acc[mt][0] = MFMA16(a, b0, acc[mt][0]);
      acc[mt][1] = MFMA16(a, b1, acc[mt][1]);
    }
  }
}

// y1 = relu(bn1(W1@X)); out = relu(bn2(W2@y1) + resid). Leaves post-relu f32 in acc.
__device__ __forceinline__ void res_block(const u16* __restrict__ W1, const u16* __restrict__ W2,
    const float* __restrict__ bn1, const float* __restrict__ bn2,
    u16* __restrict__ Xw, int q, int l15, u32 resid[8][2][2], f32x4 acc[8][2], bool writeback){
  zero_acc(acc);
  conv_step(W1, Xw, q, l15, acc);
  #pragma unroll
  for (int mt = 0; mt < 8; ++mt){
    f32x4 sc = *(const f32x4*)(bn1 + mt*16 + q*4);
    f32x4 bi = *(const f32x4*)(bn1 + 128 + mt*16 + q*4);
    #pragma unroll
    for (int nt = 0; nt < 2; ++nt){
      float y0 = fmaxf(fmaf(acc[mt][nt][0], sc[0], bi[0]), 0.f);
      float y1 = fmaxf(fmaf(acc[mt][nt][1], sc[1], bi[1]), 0.f);
      float y2 = fmaxf(fmaf(acc[mt][nt][2], sc[2], bi[2]), 0.f);
      float y3 = fmaxf(fmaf(acc[mt][nt][3], sc[3], bi[3]), 0.f);
      *(uint2*)(Xw + (nt*16 + l15)*LDSPAD + mt*16 + q*4) = make_uint2(pack2bf(y0,y1), pack2bf(y2,y3));
    }
  }
  __syncthreads();
  zero_acc(acc);
  conv_step(W2, Xw, q, l15, acc);
  #pragma unroll
  for (int mt = 0; mt < 8; ++mt){
    f32x4 sc = *(const f32x4*)(bn2 + mt*16 + q*4);
    f32x4 bi = *(const f32x4*)(bn2 + 128 + mt*16 + q*4);
    #pragma unroll
    for (int nt = 0; nt < 2; ++nt){
      float r0 = bf2f((u16)(resid[mt][nt][0] & 0xFFFFu));
      float r1 = bf2f((u16)(resid[mt][nt][0] >> 16));
      float r2 = bf2f((u16)(resid[mt][nt][1] & 0xFFFFu));
      float r3 = bf2f((u16)(resid[mt][nt][1] >> 16));
      float y0 = fmaxf(fmaf(acc[mt][nt][0], sc[0], bi[0]) + r0, 0.f);
      float y1 = fmaxf(fmaf(acc[mt][nt][1], sc[1], bi[1]) + r1, 0.f);
      float y2 = fmaxf(fmaf(acc[mt][nt][2], sc[2], bi[2]) + r2, 0.f);
      float y3 = fmaxf(fmaf(acc[mt][nt][3], sc[3], bi[3]) + r3, 0.f);
      acc[mt][nt][0] = y0; acc[mt][nt][1] = y1; acc[mt][nt][2] = y2; acc[mt][nt][3] = y3;
      if (writeback){
        u32 p0 = pack2bf(y0,y1), p1 = pack2bf(y2,y3);
        resid[mt][nt][0] = p0; resid[mt][nt][1] = p1;
        *(uint2*)(Xw + (nt*16 + l15)*LDSPAD + mt*16 + q*4) = make_uint2(p0, p1);
      }
    }
  }
  if (writeback) __syncthreads();
}

// ---------------------------------------------------------------------------
// knn (register-resident result) + mid, one wave per center. Block-level gate
// already passed; per-wave verify spin (intra-batch stores unordered).
// Barrier count per call is identical for all waves (safe in persistent loop).
// ---------------------------------------------------------------------------
__device__ void knnmid_path(const float* __restrict__ xyz, const float* __restrict__ feat,
    const u16* __restrict__ te_w, const u16* __restrict__ pre_w1, const u16* __restrict__ pre_w2,
    const float* __restrict__ bns, int* __restrict__ fps_idx,
    u16* __restrict__ x_mid, u32* __restrict__ done, float* __restrict__ out_xyz,
    u16* __restrict__ Xw, float* __restrict__ scrw, int g, int lane){
  #pragma clang fp contract(off)
  const int b = g >> 11;
  const float* xb = xyz + (size_t)b * N_ * 3;

  int raw;
  for (;;){
    raw = __hip_atomic_load(fps_idx + g, __ATOMIC_RELAXED, __HIP_MEMORY_SCOPE_AGENT);
    if (raw >= 0) break;     // usually already visible (block gate passed)
    __builtin_amdgcn_s_sleep(2);
  }
  const int ci = raw & (N_ - 1);                // clamp: fault-proof
  const float cx = xb[ci*3], cy = xb[ci*3+1], cz = xb[ci*3+2];
  if (lane < 3) out_xyz[g*3 + lane] = xb[ci*3 + lane];

  // --- knn: sorted 64-slot lane list, threshold slot 31 (exact f32 + lex tie)
  float rd = __uint_as_float(0x7F800000u); int ri = 0x7FFFFFFF;
  float r31d = rd; int r31i = ri;
  for (int c = 0; c < N_/64; ++c){
    const int pid = c*64 + lane;
    float dx = xb[pid*3]   - cx;
    float dy = xb[pid*3+1] - cy;
    float dz = xb[pid*3+2] - cz;
    float t0 = dx*dx, t1 = dy*dy, t2 = dz*dz;
    float d2 = (t0 + t1) + t2;
    u64 m = __ballot((d2 < r31d) || (d2 == r31d && pid < r31i));
    while (m){
      int l = __ffsll((long long)m) - 1; m &= m - 1;
      float v = __shfl(d2, l); int vi = c*64 + l;
      if (!((v < r31d) || (v == r31d && vi < r31i))) continue;  // re-check vs updated threshold
      bool lt = (rd < v) || (rd == v && ri < vi);
      int pos = __popcll(__ballot(lt));
      float prd = __shfl_up(rd, 1); int pri = __shfl_up(ri, 1);
      if (lane == pos){ rd = v; ri = vi; }
      else if (lane > pos){ rd = prd; ri = pri; }
      r31d = __shfl(rd, 31); r31i = __shfl(ri, 31);
    }
  }
  // neighbor k (k<32) lives in lane k's ri - handed to mid via shfl below.

  // --- mid: gather -> te conv -> 2 pre res-blocks -> maxpool
  const int q = lane >> 4, l15 = lane & 15;
  const float* fb = feat + (size_t)b * N_ * CIN;
  #pragma unroll
  for (int it = 0; it < 4; ++it){
    int lidx = it*64 + lane;
    int kq = lidx & 7;                            // 8-ch chunk
    int col = it*8 + (lane >> 3);                 // col<32
    int nb = __shfl(ri, col) & (N_ - 1);
    f32x4 a0 = *(const f32x4*)(fb + (size_t)nb*CIN + kq*8);
    f32x4 a1 = *(const f32x4*)(fb + (size_t)nb*CIN + kq*8 + 4);
    *(uint2*)(Xw + col*LDSPAD + kq*8)     = make_uint2(pack2bf(a0[0],a0[1]), pack2bf(a0[2],a0[3]));
    *(uint2*)(Xw + col*LDSPAD + kq*8 + 4) = make_uint2(pack2bf(a1[0],a1[1]), pack2bf(a1[2],a1[3]));
    f32x4 c0 = *(const f32x4*)(fb + (size_t)ci*CIN + kq*8);
    f32x4 c1 = *(const f32x4*)(fb + (size_t)ci*CIN + kq*8 + 4);
    *(uint2*)(Xw + col*LDSPAD + 64 + kq*8)     = make_uint2(pack2bf(c0[0],c0[1]), pack2bf(c0[2],c0[3]));
    *(uint2*)(Xw + col*LDSPAD + 64 + kq*8 + 4) = make_uint2(pack2bf(c1[0],c1[1]), pack2bf(c1[2],c1[3]));
  }
  __syncthreads();

  f32x4 acc[8][2];
  u32 resid[8][2][2];
  zero_acc(acc);
  conv_step(te_w, Xw, q, l15, acc);
  #pragma unroll
  for (int mt = 0; mt < 8; ++mt){
    f32x4 sc = *(const f32x4*)(bns + mt*16 + q*4);
    f32x4 bi = *(const f32x4*)(bns + 128 + mt*16 + q*4);
    #pragma unroll
    for (int nt = 0; nt < 2; ++nt){
      float y0 = fmaxf(fmaf(acc[mt][nt][0], sc[0], bi[0]), 0.f);
      float y1 = fmaxf(fmaf(acc[mt][nt][1], sc[1], bi[1]), 0.f);
      float y2 = fmaxf(fmaf(acc[mt][nt][2], sc[2], bi[2]), 0.f);
      float y3 = fmaxf(fmaf(acc[mt][nt][3], sc[3], bi[3]), 0.f);
      u32 p0 = pack2bf(y0,y1), p1 = pack2bf(y2,y3);
      resid[mt][nt][0] = p0; resid[mt][nt][1] = p1;
      *(uint2*)(Xw + (nt*16 + l15)*LDSPAD + mt*16 + q*4) = make_uint2(p0, p1);
    }
  }
  __syncthreads();

  res_block(pre_w1,             pre_w2,             bns + 256, bns + 512,  Xw, q, l15, resid, acc, true);
  res_block(pre_w1 + COUT*COUT, pre_w2 + COUT*COUT, bns + 768, bns + 1024, Xw, q, l15, resid, acc, false);

  // maxpool over 32 cols (nt pair + butterfly over low-4 lane bits)
  float mx[8][4];
  #pragma unroll
  for (int mt = 0; mt < 8; ++mt)
    #pragma unroll
    for (int r = 0; r < 4; ++r){
      float m0 = fmaxf(acc[mt][0][r], acc[mt][1][r]);
      #pragma unroll
      for (int off = 1; off < 16; off <<= 1) m0 = fmaxf(m0, __shfl_xor(m0, off));
      mx[mt][r] = m0;
    }
  if (l15 == 0){
    #pragma unroll
    for (int mt = 0; mt < 8; ++mt){
      f32x4 vv; vv[0] = mx[mt][0]; vv[1] = mx[mt][1]; vv[2] = mx[mt][2]; vv[3] = mx[mt][3];
      *(f32x4*)(scrw + mt*16 + q*4) = vv;
    }
  }
  __syncthreads();
  float v0 = scrw[lane*2], v1 = scrw[lane*2 + 1];
  *(u32*)(x_mid + (size_t)g*COUT + lane*2) = pack2bf(v0, v1);
  if (lane == 0)   // release: s_waitcnt is wave-level -> covers all lanes' stores
    __hip_atomic_store(done + g, 1u, __ATOMIC_RELEASE, __HIP_MEMORY_SCOPE_AGENT);
}

// ---------------------------------------------------------------------------
// pos: 2 res-blocks over (B,128,2048); one wave per 32 columns. Spins on the
// 32 done flags of its column group, acquire-fences, then reads x_mid.
// ---------------------------------------------------------------------------
__device__ void pos_path(const u16* __restrict__ x_mid,
    const u16* __restrict__ pos_w1, const u16* __restrict__ pos_w2,
    const float* __restrict__ bns, float* __restrict__ out_x,
    u32* __restrict__ done, u16* __restrict__ Xw, int g, int lane){
  const int q = lane >> 4, l15 = lane & 15;
  const int gc0 = g * 32;
  const int b = gc0 >> 11, s0 = gc0 & 2047;
  for (;;){
    u32 d = (lane < 32)
      ? __hip_atomic_load(done + gc0 + lane, __ATOMIC_RELAXED, __HIP_MEMORY_SCOPE_AGENT)
      : 1u;
    if (__all(d != 0)) break;
    __builtin_amdgcn_s_sleep(16);
  }
  __builtin_amdgcn_fence(__ATOMIC_ACQUIRE, "agent");
  #pragma unroll
  for (int it = 0; it < 8; ++it){
    int lidx = it*64 + lane;
    int col = lidx >> 4, kq = lidx & 15;
    uint4 v = *(const uint4*)(x_mid + (size_t)(gc0 + col)*COUT + kq*8);
    *(uint4*)(Xw + col*LDSPAD + kq*8) = v;
  }
  __syncthreads();
  u32 resid[8][2][2];
  #pragma unroll
  for (int mt = 0; mt < 8; ++mt)
    #pragma unroll
    for (int nt = 0; nt < 2; ++nt){
      uint2 rr = *(const uint2*)(Xw + (nt*16 + l15)*LDSPAD + mt*16 + q*4);
      resid[mt][nt][0] = rr.x; resid[mt][nt][1] = rr.y;
    }
  f32x4 acc[8][2];
  res_block(pos_w1,             pos_w2,             bns + 1280, bns + 1536, Xw, q, l15, resid, acc, true);
  res_block(pos_w1 + COUT*COUT, pos_w2 + COUT*COUT, bns + 1792, bns + 2048, Xw, q, l15, resid, acc, false);
  #pragma unroll
  for (int mt = 0; mt < 8; ++mt)
    #pragma unroll
    for (int nt = 0; nt < 2; ++nt)
      #pragma unroll
      for (int r = 0; r < 4; ++r){
        int row = mt*16 + q*4 + r;
        int colx = s0 + nt*16 + l15;
        out_x[(size_t)(b*COUT + row)*NS + colx] = acc[mt][nt][r];
      }
}

// ---------------------------------------------------------------------------
#define GRID_FPS    B_                 // 8
#define GRID_PREP   1
#define GRID_KM_BLK 96                 // persistent; 2048 units of 8 centers
#define KM_UNITS    (B_*NS/8)          // 2048
#define GRID_POS_BLK 16                // persistent; 64 units of 8 col-groups
#define POS_UNITS   (B_*NS/K_/8)       // 64

__global__ __launch_bounds__(512) void mega_kernel(
    const float* __restrict__ xyz, const float* __restrict__ feat,
    const float* __restrict__ s_te, const float* __restrict__ s_pre1,
    const float* __restrict__ s_pre2, const float* __restrict__ s_pos1,
    const float* __restrict__ s_pos2, BnPtrs bp,
    u16* __restrict__ te_w, u16* __restrict__ pre_w1, u16* __restrict__ pre_w2,
    u16* __restrict__ pos_w1, u16* __restrict__ pos_w2,
    float* __restrict__ bns, int* __restrict__ fps_idx,
    u16* __restrict__ x_mid, u32* __restrict__ done, u32* __restrict__ wready,
    float* __restrict__ out_xyz, float* __restrict__ out_x){
  __shared__ ShAll sh;
  const int bid = blockIdx.x;
  const int t = threadIdx.x;
  const int wid = t >> 6, lane = t & 63;
  if (bid < GRID_FPS){
    fps_path(xyz, fps_idx, sh.f, bid, t);
  } else if (bid < GRID_FPS + GRID_PREP){
    prep_path(s_te, s_pre1, s_pre2, s_pos1, s_pos2,
              te_w, pre_w1, pre_w2, pos_w1, pos_w2, bp, bns, wready, t);
  } else if (bid < GRID_FPS + GRID_PREP + GRID_KM_BLK){
    // persistent knn+mid: block ib loops units ib, ib+96, ... Unit j covers
    // batch j&7, centers (j>>3)*8 .. +7 (interleaved mapping). Stride 96 ==
    // 0 mod 8 -> each block stays in ONE batch, walking forward in stream
    // order. Barrier count per unit identical across waves -> loop-safe.
    const int ib = bid - GRID_FPS - GRID_PREP;
    for (int j = ib; j < KM_UNITS; j += GRID_KM_BLK){
      const int g0 = (j & 7) * NS + (j >> 3) * 8;
      if (t == 0){
        while (__hip_atomic_load(wready, __ATOMIC_RELAXED, __HIP_MEMORY_SCOPE_AGENT) == 0u ||
               __hip_atomic_load(fps_idx + g0 + 7, __ATOMIC_RELAXED,
                                 __HIP_MEMORY_SCOPE_AGENT) < 0)
          __builtin_amdgcn_s_sleep(16);
      }
      __syncthreads();
      knnmid_path(xyz, feat, te_w, pre_w1, pre_w2, bns, fps_idx, x_mid, done, out_xyz,
                  sh.m.X[wid], sh.m.scr[wid], g0 + wid, lane);
      __syncthreads();
    }
  } else {
    // persistent pos: block loops units; unit j = 8 col-groups (interleaved)
    const int ib = bid - GRID_FPS - GRID_PREP - GRID_KM_BLK;
    for (int j = ib; j < POS_UNITS; j += GRID_POS_BLK){
      const int idx = j*8 + wid;                          // 0..511
      const int g = (idx & 7) * (NS/K_) + (idx >> 3);     // interleave batches
      pos_path(x_mid, pos_w1, pos_w2, bns, out_x, done, sh.p.X[wid], g, lane);
      __syncthreads();
    }
  }
}

// ---------------------------------------------------------------------------
extern "C" void kernel_launch(void* const* d_in, const int* in_sizes, int n_in,
                              void* d_out, int out_size, void* d_ws, size_t ws_size,
                              hipStream_t stream){
  (void)in_sizes; (void)n_in; (void)out_size; (void)ws_size;
  const float* xyz    = (const float*)d_in[0];
  const float* feat   = (const float*)d_in[1];

  // ws layout (16B aligned, ~4.7 MB total):
  char* ws = (char*)d_ws;
  float* bns     = (float*)ws;                          // 16 KiB (9.2 used)
  u32*   wready  = (u32*)(ws + 12288);                  // 4B in bns spare
  u16*   wbf     = (u16*)(ws + 16384);                  // 288 KiB bf16 weights
  int*   fps_idx = (int*)(ws + 16384 + 294912);         // 64 KiB
  u32*   done    = (u32*)(ws + 16384 + 294912 + 65536); // 64 KiB
  u16*   x_mid   = (u16*)(ws + 16384 + 294912 + 65536 + 65536); // 4 MiB
  float* out_xyz = (float*)d_out;                       // (8,2048,3) f32
  float* out_x   = (float*)d_out + B_*NS*3;             // (8,128,2048) f32

  // bf16 weight staging: te(16384) pre_w1(32768) pre_w2(32768) pos_w1(32768) pos_w2(32768)
  u16* te_w   = wbf;
  u16* pre_w1 = wbf + 16384;
  u16* pre_w2 = wbf + 49152;
  u16* pos_w1 = wbf + 81920;
  u16* pos_w2 = wbf + 114688;

  // dict order: te_g/b/m/v = 3..6 ; pre: w1,w2,g1,g2,b1,b2,m1,m2,v1,v2 = 7..16 ; pos = 17..26
  BnPtrs bp;
  const int gi[9] = {3, 9, 10, 9, 10, 19, 20, 19, 20};
  const int bbi[9]= {4, 11,12, 11,12, 21, 22, 21, 22};
  const int mi[9] = {5, 13,14, 13,14, 23, 24, 23, 24};
  const int vi[9] = {6, 15,16, 15,16, 25, 26, 25, 26};
  const int of[9] = {0, 0, 0, 128,128, 0, 0, 128,128};
  for (int k = 0; k < 9; ++k){
    bp.g[k] = (const float*)d_in[gi[k]]  + of[k];
    bp.b[k] = (const float*)d_in[bbi[k]] + of[k];
    bp.m[k] = (const float*)d_in[mi[k]]  + of[k];
    bp.v[k] = (const float*)d_in[vi[k]]  + of[k];
  }

  clear_kernel<<<64, 256, 0, stream>>>(fps_idx, done, wready);
  mega_kernel<<<GRID_FPS + GRID_PREP + GRID_KM_BLK + GRID_POS_BLK, 512, 0, stream>>>(
      xyz, feat,
      (const float*)d_in[2], (const float*)d_in[7], (const float*)d_in[8],
      (const float*)d_in[17], (const float*)d_in[18], bp,
      te_w, pre_w1, pre_w2, pos_w1, pos_w2,
      bns, fps_idx, x_mid, done, wready, out_xyz, out_x);
}

// Round 10
// 2808.305 us; speedup vs baseline: 1.2441x; 1.2441x over previous
//
#include <hip/hip_runtime.h>

typedef unsigned short u16;
typedef unsigned int   u32;
typedef unsigned long long u64;

#define B_    8
#define N_    8192
#define CIN   64
#define COUT  128
#define NS    2048
#define K_    32
#define LDSPAD 136   // 128 + 8 bf16: breaks bank conflicts on column stride

typedef __attribute__((ext_vector_type(8))) short short8;
typedef __attribute__((ext_vector_type(4))) float f32x4;
typedef __attribute__((ext_vector_type(2))) float f32x2;

#define MFMA16(a,b,c) __builtin_amdgcn_mfma_f32_16x16x32_bf16(a,b,c,0,0,0)

__device__ __forceinline__ u16 f2bf(float f){
  u32 u = __float_as_uint(f);
  return (u16)((u + 0x7FFFu + ((u >> 16) & 1u)) >> 16);   // RNE, finite values only
}
__device__ __forceinline__ float bf2f(u16 h){ u32 u = ((u32)h) << 16; return __uint_as_float(u); }
__device__ __forceinline__ u32 pack2bf(float lo, float hi){ return (u32)f2bf(lo) | ((u32)f2bf(hi) << 16); }

// ---------------------------------------------------------------------------
// Weight f32 -> bf16 conversion (one-time prep into ws)
// ---------------------------------------------------------------------------
__global__ void wcvt_kernel(const float* __restrict__ s, u16* __restrict__ d, int n){
  int i = blockIdx.x * 256 + threadIdx.x;
  if (i < n) d[i] = f2bf(s[i]);
}

// fps_idx -> -1 sentinel, done flags -> 0 (per launch; graph replay reuses ws)
__global__ void clear_kernel(int* __restrict__ fps_idx, u32* __restrict__ done){
  int i = blockIdx.x * 256 + threadIdx.x;
  if (i < B_*NS){ fps_idx[i] = -1; done[i] = 0u; }
}

// ---------------------------------------------------------------------------
// BN constants: scale = g/sqrt(v+eps), bias = b - m*scale  (all f32 inputs)
// set order: 0=te, 1/2=pre0.bn1/bn2, 3/4=pre1.bn1/bn2, 5/6=pos0, 7/8=pos1
// ---------------------------------------------------------------------------
struct BnPtrs { const float* g[9]; const float* b[9]; const float* m[9]; const float* v[9]; };

__global__ void bn_pre_kernel(BnPtrs p, float* __restrict__ bns){
  int set = blockIdx.x, c = threadIdx.x;
  float sc = p.g[set][c] / sqrtf(p.v[set][c] + 1e-5f);
  bns[set*256 + c]       = sc;
  bns[set*256 + 128 + c] = p.b[set][c] - p.m[set][c] * sc;
}

// ---------------------------------------------------------------------------
// MEGA-KERNEL — round-6 configuration (session best: 2816us total), locked.
// Probe ledger (r0-r9): FPS step is an inherent serial chain (argmax ->
// broadcast -> distance update x2047). Null/regressed probes: instruction
// cuts, packed math, LDS->reg, 3 combine topologies, drain-free barriers,
// publish batching, wave topology, persistent/capped consumers. Wins kept:
//  (a) streaming producer/consumer mega-kernel (consumers hidden in the fps
//      window; serial-kernel era paid them as +750us),
//  (b) INTERLEAVED consumer mapping g0=(i%8)*2048+(i/8)*8 — resident fleet
//      covers all 8 batches' stream frontiers (FETCH 50->12GB, no tail),
//  (c) FPS v9: points in registers, winner coords from winner lane's regs,
//      lgkm-only loop barrier, batched relaxed publish.
//   blocks 0..7        : fps (one batch each; 82KB union -> 1 block/CU)
//   blocks 8..2055     : knn+mid fused, 8 centers/block, one-shot
//   blocks 2056..2119  : pos, 8 col-groups/block, one-shot
// ---------------------------------------------------------------------------
struct ShFps {
  __align__(16) u64  keyA[2][8];
  __align__(16) f32x4 cA[2][8];
};
struct ShMid {
  __align__(16) u16 X[8][32*LDSPAD];
  __align__(16) float scr[8][128];
};
struct ShPos {
  __align__(16) u16 X[8][32*LDSPAD];
};
union ShAll { ShFps f; ShMid m; ShPos p; char pad[83968]; };  // 82KB -> 1 blk/CU

// loop barrier WITHOUT vmem drain: only LDS ordering is needed inside the fps
// loop (publish stores are fire-and-forget relaxed atomics). sched_barrier
// fences prevent hipcc from hoisting ops across the asm (guide rule 18).
__device__ __forceinline__ void lds_barrier(){
  __builtin_amdgcn_sched_barrier(0);
  asm volatile("s_waitcnt lgkmcnt(0)\n\ts_barrier" ::: "memory");
  __builtin_amdgcn_sched_barrier(0);
}

// ---------------------------------------------------------------------------
// FPS v9 core. Exact f32 (contract off); tie -> lowest index (bit-identical
// selection to v5: D values equal bit-for-bit at every step).
// ---------------------------------------------------------------------------
#define DPP_UMAX(x, ctrl) { \
  u32 o = (u32)__builtin_amdgcn_update_dpp((int)(x), (int)(x), ctrl, 0xf, 0xf, false); \
  x = (o > x) ? o : x; }

__device__ __forceinline__ u32 wave_umax63(u32 x){
  DPP_UMAX(x, 0x111)  // row_shr:1
  DPP_UMAX(x, 0x112)  // row_shr:2
  DPP_UMAX(x, 0x114)  // row_shr:4
  DPP_UMAX(x, 0x118)  // row_shr:8
  DPP_UMAX(x, 0x142)  // row_bcast:15
  DPP_UMAX(x, 0x143)  // row_bcast:31
  return (u32)__builtin_amdgcn_readlane((int)x, 63);
}

// pair m covers points base+2m, base+2m+1. Packed distance update:
// dd = (dx*dx + dy*dy) + dz*dz elementwise == scalar assoc of np.sum axis=-1.
#define FPS_PAIR(m) { \
  f32x2 dx = PXr##m - lx2; \
  f32x2 dy = PYr##m - ly2; \
  f32x2 dz = PZr##m - lz2; \
  f32x2 t0 = dx*dx; \
  f32x2 t1 = dy*dy; \
  f32x2 t2 = dz*dz; \
  f32x2 dd = (t0 + t1) + t2; \
  f32x2 nd; \
  nd.x = fminf(Dr##m.x, dd.x); \
  nd.y = fminf(Dr##m.y, dd.y); \
  Dr##m = nd; \
  fmA = fmaxf(fmA, nd.x); \
  fmB = fmaxf(fmB, nd.y); }

// descending order: last matching assignment wins -> lowest k (exact ties).
// Winner coords selected from THIS lane's registers (no LDS round-trip).
#define FPS_SELK(m) { \
  if (Dr##m.y == wmf){ kk = 2*m + 1; wx = PXr##m.y; wy = PYr##m.y; wz = PZr##m.y; } \
  if (Dr##m.x == wmf){ kk = 2*m;     wx = PXr##m.x; wy = PYr##m.x; wz = PZr##m.x; } }

__device__ __forceinline__ void selmax(u64& ka, f32x4& ca, u64 kb, f32x4 cb){
  bool c = kb > ka;
  ka = c ? kb : ka;
  ca = c ? cb : ca;
}

__device__ void fps_path(const float* __restrict__ xyz, int* __restrict__ fps_idx,
                         ShFps& S, int b, int t){
  #pragma clang fp contract(off)
  const int lane = t & 63, wv = t >> 6;
  const float* xb = xyz + (size_t)b * N_ * 3;
  const int base = t * 16;
  // global -> registers: this thread's 16 points are bytes [base*12, +192),
  // contiguous and 16B-aligned -> 12 coalesced f32x4 loads.
  f32x4 raw0, raw1, raw2, raw3, raw4, raw5, raw6, raw7, raw8, raw9, rawA, rawB;
  {
    const f32x4* xv = (const f32x4*)(xb + (size_t)base * 3);
    raw0 = xv[0]; raw1 = xv[1]; raw2 = xv[2];  raw3 = xv[3];
    raw4 = xv[4]; raw5 = xv[5]; raw6 = xv[6];  raw7 = xv[7];
    raw8 = xv[8]; raw9 = xv[9]; rawA = xv[10]; rawB = xv[11];
  }
  // unpack [x0 y0 z0 x1 y1 z1 ...] into coord pairs (all static indices)
  f32x2 PXr0,PXr1,PXr2,PXr3,PXr4,PXr5,PXr6,PXr7;
  f32x2 PYr0,PYr1,PYr2,PYr3,PYr4,PYr5,PYr6,PYr7;
  f32x2 PZr0,PZr1,PZr2,PZr3,PZr4,PZr5,PZr6,PZr7;
  #define GETF(k) (k<4?raw0[(k)&3]:k<8?raw1[(k)&3]:k<12?raw2[(k)&3]:k<16?raw3[(k)&3]: \
                   k<20?raw4[(k)&3]:k<24?raw5[(k)&3]:k<28?raw6[(k)&3]:k<32?raw7[(k)&3]: \
                   k<36?raw8[(k)&3]:k<40?raw9[(k)&3]:k<44?rawA[(k)&3]:rawB[(k)&3])
  #define SETP(m) { \
    PXr##m.x = GETF(6*m+0); PXr##m.y = GETF(6*m+3); \
    PYr##m.x = GETF(6*m+1); PYr##m.y = GETF(6*m+4); \
    PZr##m.x = GETF(6*m+2); PZr##m.y = GETF(6*m+5); }
  SETP(0) SETP(1) SETP(2) SETP(3) SETP(4) SETP(5) SETP(6) SETP(7)
  #undef SETP
  #undef GETF
  if (t == 0)
    __hip_atomic_store(fps_idx + b*NS, 0, __ATOMIC_RELAXED, __HIP_MEMORY_SCOPE_AGENT);
  f32x2 Dr0,Dr1,Dr2,Dr3,Dr4,Dr5,Dr6,Dr7;
  Dr0=Dr1=Dr2=Dr3=Dr4=Dr5=Dr6=Dr7=(f32x2){1e10f,1e10f};
  const float sx = xb[0], sy = xb[1], sz = xb[2];   // point 0 is the seed
  f32x2 lx2 = {sx,sx}, ly2 = {sy,sy}, lz2 = {sz,sz};
  int my_pi = 0;                                // batched-publish register slot
  for (int s = 0; s < NS - 1; ++s){
    float fmA = 0.f, fmB = 0.f;                 // dists >= 0
    FPS_PAIR(0) FPS_PAIR(1) FPS_PAIR(2) FPS_PAIR(3)
    FPS_PAIR(4) FPS_PAIR(5) FPS_PAIR(6) FPS_PAIR(7)
    const float fm = fmaxf(fmA, fmB);
    const u32 tbm = __float_as_uint(fm);        // >=0 -> bit-max == f32-max
    const u32 wmax = wave_umax63(tbm);          // 6 VALU DPP ops + readlane
    const u64 mask = __ballot(tbm == wmax);
    const int fl = __ffsll((long long)mask) - 1;   // lowest lane = lowest index
    const int sl = s & 1;
    if (lane == fl){
      const float wmf = __uint_as_float(wmax);  // dists +0-or-positive:
      int kk = 0;                               // f32 eq == bit eq here
      float wx = PXr0.x, wy = PYr0.x, wz = PZr0.x;
      FPS_SELK(7) FPS_SELK(6) FPS_SELK(5) FPS_SELK(4)
      FPS_SELK(3) FPS_SELK(2) FPS_SELK(1) FPS_SELK(0)
      const int pi = base + kk;                  // first max index in this wave
      S.keyA[sl][wv] = ((u64)wmax << 13) | (u64)(8191 - pi);
      f32x4 c; c[0] = wx; c[1] = wy; c[2] = wz; c[3] = 0.f;
      S.cA[sl][wv] = c;
    }
    lds_barrier();                              // records visible; no vm drain
    // all threads: 16 broadcast reads + depth-3 tree select over UNIQUE keys
    u64 k0 = S.keyA[sl][0], k1 = S.keyA[sl][1], k2 = S.keyA[sl][2], k3 = S.keyA[sl][3];
    u64 k4 = S.keyA[sl][4], k5 = S.keyA[sl][5], k6 = S.keyA[sl][6], k7 = S.keyA[sl][7];
    f32x4 c0 = S.cA[sl][0], c1 = S.cA[sl][1], c2 = S.cA[sl][2], c3 = S.cA[sl][3];
    f32x4 c4 = S.cA[sl][4], c5 = S.cA[sl][5], c6 = S.cA[sl][6], c7 = S.cA[sl][7];
    selmax(k0,c0,k1,c1); selmax(k2,c2,k3,c3); selmax(k4,c4,k5,c5); selmax(k6,c6,k7,c7);
    selmax(k0,c0,k2,c2); selmax(k4,c4,k6,c6);
    selmax(k0,c0,k4,c4);
    lx2.x = c0[0]; lx2.y = c0[0];
    ly2.x = c0[1]; ly2.y = c0[1];
    lz2.x = c0[2]; lz2.y = c0[2];
    // batched publish (16): step s fills lane (s&15); at s&15==15 wave-0
    // lanes 0..15 store slots s-14..s+1 (relaxed agent; never drained in-loop)
    const int pi_out = 8191 - (int)(k0 & 0x1FFFull);
    if (lane == (s & 15)) my_pi = pi_out;
    if ((s & 15) == 15 && t < 16)
      __hip_atomic_store(fps_idx + b*NS + s - 14 + t, my_pi,
                         __ATOMIC_RELAXED, __HIP_MEMORY_SCOPE_AGENT);
  }
  // steps 2032..2046 filled lanes 0..14 -> slots 2033..2047
  if (t < 15)
    __hip_atomic_store(fps_idx + b*NS + (NS - 15) + t, my_pi,
                       __ATOMIC_RELAXED, __HIP_MEMORY_SCOPE_AGENT);
}

// ---------------------------------------------------------------------------
// Conv stack helpers (unchanged, m89-verified MFMA layouts).
// ---------------------------------------------------------------------------
__device__ __forceinline__ void zero_acc(f32x4 acc[8][2]){
  #pragma unroll
  for (int mt = 0; mt < 8; ++mt)
    #pragma unroll
    for (int nt = 0; nt < 2; ++nt){
      acc[mt][nt][0] = 0.f; acc[mt][nt][1] = 0.f; acc[mt][nt][2] = 0.f; acc[mt][nt][3] = 0.f;
    }
}

__device__ __forceinline__ void conv_step(const u16* __restrict__ W, const u16* __restrict__ Xw,
                                          int q, int l15, f32x4 acc[8][2]){
  #pragma unroll
  for (int kk = 0; kk < 4; ++kk){
    short8 b0 = *(const short8*)(Xw + l15*LDSPAD + kk*32 + q*8);
    short8 b1 = *(const short8*)(Xw + (16 + l15)*LDSPAD + kk*32 + q*8);
    #pragma unroll
    for (int mt = 0; mt < 8; ++mt){
      short8 a = *(const short8*)(W + (size_t)(mt*16 + l15)*COUT + kk*32 + q*8);
      acc[mt][0] = MFMA16(a, b0, acc[mt][0]);
      acc[mt][1] = MFMA16(a, b1, acc[mt][1]);
    }
  }
}

// y1 = relu(bn1(W1@X)); out = relu(bn2(W2@y1) + resid). Leaves post-relu f32 in acc.
__device__ __forceinline__ void res_block(const u16* __restrict__ W1, const u16* __restrict__ W2,
    const float* __restrict__ bn1, const float* __restrict__ bn2,
    u16* __restrict__ Xw, int q, int l15, u32 resid[8][2][2], f32x4 acc[8][2], bool writeback){
  zero_acc(acc);
  conv_step(W1, Xw, q, l15, acc);
  #pragma unroll
  for (int mt = 0; mt < 8; ++mt){
    f32x4 sc = *(const f32x4*)(bn1 + mt*16 + q*4);
    f32x4 bi = *(const f32x4*)(bn1 + 128 + mt*16 + q*4);
    #pragma unroll
    for (int nt = 0; nt < 2; ++nt){
      float y0 = fmaxf(fmaf(acc[mt][nt][0], sc[0], bi[0]), 0.f);
      float y1 = fmaxf(fmaf(acc[mt][nt][1], sc[1], bi[1]), 0.f);
      float y2 = fmaxf(fmaf(acc[mt][nt][2], sc[2], bi[2]), 0.f);
      float y3 = fmaxf(fmaf(acc[mt][nt][3], sc[3], bi[3]), 0.f);
      *(uint2*)(Xw + (nt*16 + l15)*LDSPAD + mt*16 + q*4) = make_uint2(pack2bf(y0,y1), pack2bf(y2,y3));
    }
  }
  __syncthreads();
  zero_acc(acc);
  conv_step(W2, Xw, q, l15, acc);
  #pragma unroll
  for (int mt = 0; mt < 8; ++mt){
    f32x4 sc = *(const f32x4*)(bn2 + mt*16 + q*4);
    f32x4 bi = *(const f32x4*)(bn2 + 128 + mt*16 + q*4);
    #pragma unroll
    for (int nt = 0; nt < 2; ++nt){
      float r0 = bf2f((u16)(resid[mt][nt][0] & 0xFFFFu));
      float r1 = bf2f((u16)(resid[mt][nt][0] >> 16));
      float r2 = bf2f((u16)(resid[mt][nt][1] & 0xFFFFu));
      float r3 = bf2f((u16)(resid[mt][nt][1] >> 16));
      float y0 = fmaxf(fmaf(acc[mt][nt][0], sc[0], bi[0]) + r0, 0.f);
      float y1 = fmaxf(fmaf(acc[mt][nt][1], sc[1], bi[1]) + r1, 0.f);
      float y2 = fmaxf(fmaf(acc[mt][nt][2], sc[2], bi[2]) + r2, 0.f);
      float y3 = fmaxf(fmaf(acc[mt][nt][3], sc[3], bi[3]) + r3, 0.f);
      acc[mt][nt][0] = y0; acc[mt][nt][1] = y1; acc[mt][nt][2] = y2; acc[mt][nt][3] = y3;
      if (writeback){
        u32 p0 = pack2bf(y0,y1), p1 = pack2bf(y2,y3);
        resid[mt][nt][0] = p0; resid[mt][nt][1] = p1;
        *(uint2*)(Xw + (nt*16 + l15)*LDSPAD + mt*16 + q*4) = make_uint2(p0, p1);
      }
    }
  }
  if (writeback) __syncthreads();
}

// ---------------------------------------------------------------------------
// knn (register-resident result) + mid, one wave per center. Block-level gate
// already passed; per-wave verify spin (intra-batch stores unordered).
// ---------------------------------------------------------------------------
__device__ void knnmid_path(const float* __restrict__ xyz, const float* __restrict__ feat,
    const u16* __restrict__ te_w, const u16* __restrict__ pre_w1, const u16* __restrict__ pre_w2,
    const float* __restrict__ bns, int* __restrict__ fps_idx,
    u16* __restrict__ x_mid, u32* __restrict__ done, float* __restrict__ out_xyz,
    u16* __restrict__ Xw, float* __restrict__ scrw, int g, int lane){
  #pragma clang fp contract(off)
  const int b = g >> 11;
  const float* xb = xyz + (size_t)b * N_ * 3;

  int raw;
  for (;;){
    raw = __hip_atomic_load(fps_idx + g, __ATOMIC_RELAXED, __HIP_MEMORY_SCOPE_AGENT);
    if (raw >= 0) break;     // usually already visible (block gate passed)
    __builtin_amdgcn_s_sleep(2);
  }
  const int ci = raw & (N_ - 1);                // clamp: fault-proof
  const float cx = xb[ci*3], cy = xb[ci*3+1], cz = xb[ci*3+2];
  if (lane < 3) out_xyz[g*3 + lane] = xb[ci*3 + lane];

  // --- knn: sorted 64-slot lane list, threshold slot 31 (exact f32 + lex tie)
  float rd = __uint_as_float(0x7F800000u); int ri = 0x7FFFFFFF;
  float r31d = rd; int r31i = ri;
  for (int c = 0; c < N_/64; ++c){
    const int pid = c*64 + lane;
    float dx = xb[pid*3]   - cx;
    float dy = xb[pid*3+1] - cy;
    float dz = xb[pid*3+2] - cz;
    float t0 = dx*dx, t1 = dy*dy, t2 = dz*dz;
    float d2 = (t0 + t1) + t2;
    u64 m = __ballot((d2 < r31d) || (d2 == r31d && pid < r31i));
    while (m){
      int l = __ffsll((long long)m) - 1; m &= m - 1;
      float v = __shfl(d2, l); int vi = c*64 + l;
      if (!((v < r31d) || (v == r31d && vi < r31i))) continue;  // re-check vs updated threshold
      bool lt = (rd < v) || (rd == v && ri < vi);
      int pos = __popcll(__ballot(lt));
      float prd = __shfl_up(rd, 1); int pri = __shfl_up(ri, 1);
      if (lane == pos){ rd = v; ri = vi; }
      else if (lane > pos){ rd = prd; ri = pri; }
      r31d = __shfl(rd, 31); r31i = __shfl(ri, 31);
    }
  }
  // neighbor k (k<32) lives in lane k's ri - handed to mid via shfl below.

  // --- mid: gather -> te conv -> 2 pre res-blocks -> maxpool
  const int q = lane >> 4, l15 = lane & 15;
  const float* fb = feat + (size_t)b * N_ * CIN;
  #pragma unroll
  for (int it = 0; it < 4; ++it){
    int lidx = it*64 + lane;
    int kq = lidx & 7;                            // 8-ch chunk
    int col = it*8 + (lane >> 3);                 // col<32
    int nb = __shfl(ri, col) & (N_ - 1);
    f32x4 a0 = *(const f32x4*)(fb + (size_t)nb*CIN + kq*8);
    f32x4 a1 = *(const f32x4*)(fb + (size_t)nb*CIN + kq*8 + 4);
    *(uint2*)(Xw + col*LDSPAD + kq*8)     = make_uint2(pack2bf(a0[0],a0[1]), pack2bf(a0[2],a0[3]));
    *(uint2*)(Xw + col*LDSPAD + kq*8 + 4) = make_uint2(pack2bf(a1[0],a1[1]), pack2bf(a1[2],a1[3]));
    f32x4 c0 = *(const f32x4*)(fb + (size_t)ci*CIN + kq*8);
    f32x4 c1 = *(const f32x4*)(fb + (size_t)ci*CIN + kq*8 + 4);
    *(uint2*)(Xw + col*LDSPAD + 64 + kq*8)     = make_uint2(pack2bf(c0[0],c0[1]), pack2bf(c0[2],c0[3]));
    *(uint2*)(Xw + col*LDSPAD + 64 + kq*8 + 4) = make_uint2(pack2bf(c1[0],c1[1]), pack2bf(c1[2],c1[3]));
  }
  __syncthreads();

  f32x4 acc[8][2];
  u32 resid[8][2][2];
  zero_acc(acc);
  conv_step(te_w, Xw, q, l15, acc);
  #pragma unroll
  for (int mt = 0; mt < 8; ++mt){
    f32x4 sc = *(const f32x4*)(bns + mt*16 + q*4);
    f32x4 bi = *(const f32x4*)(bns + 128 + mt*16 + q*4);
    #pragma unroll
    for (int nt = 0; nt < 2; ++nt){
      float y0 = fmaxf(fmaf(acc[mt][nt][0], sc[0], bi[0]), 0.f);
      float y1 = fmaxf(fmaf(acc[mt][nt][1], sc[1], bi[1]), 0.f);
      float y2 = fmaxf(fmaf(acc[mt][nt][2], sc[2], bi[2]), 0.f);
      float y3 = fmaxf(fmaf(acc[mt][nt][3], sc[3], bi[3]), 0.f);
      u32 p0 = pack2bf(y0,y1), p1 = pack2bf(y2,y3);
      resid[mt][nt][0] = p0; resid[mt][nt][1] = p1;
      *(uint2*)(Xw + (nt*16 + l15)*LDSPAD + mt*16 + q*4) = make_uint2(p0, p1);
    }
  }
  __syncthreads();

  res_block(pre_w1,             pre_w2,             bns + 256, bns + 512,  Xw, q, l15, resid, acc, true);
  res_block(pre_w1 + COUT*COUT, pre_w2 + COUT*COUT, bns + 768, bns + 1024, Xw, q, l15, resid, acc, false);

  // maxpool over 32 cols (nt pair + butterfly over low-4 lane bits)
  float mx[8][4];
  #pragma unroll
  for (int mt = 0; mt < 8; ++mt)
    #pragma unroll
    for (int r = 0; r < 4; ++r){
      float m0 = fmaxf(acc[mt][0][r], acc[mt][1][r]);
      #pragma unroll
      for (int off = 1; off < 16; off <<= 1) m0 = fmaxf(m0, __shfl_xor(m0, off));
      mx[mt][r] = m0;
    }
  if (l15 == 0){
    #pragma unroll
    for (int mt = 0; mt < 8; ++mt){
      f32x4 vv; vv[0] = mx[mt][0]; vv[1] = mx[mt][1]; vv[2] = mx[mt][2]; vv[3] = mx[mt][3];
      *(f32x4*)(scrw + mt*16 + q*4) = vv;
    }
  }
  __syncthreads();
  float v0 = scrw[lane*2], v1 = scrw[lane*2 + 1];
  *(u32*)(x_mid + (size_t)g*COUT + lane*2) = pack2bf(v0, v1);
  if (lane == 0)   // release: s_waitcnt is wave-level -> covers all lanes' stores
    __hip_atomic_store(done + g, 1u, __ATOMIC_RELEASE, __HIP_MEMORY_SCOPE_AGENT);
}

// ---------------------------------------------------------------------------
// pos: 2 res-blocks over (B,128,2048); one wave per 32 columns. Spins on the
// 32 done flags of its column group, acquire-fences, then reads x_mid.
// ---------------------------------------------------------------------------
__device__ void pos_path(const u16* __restrict__ x_mid,
    const u16* __restrict__ pos_w1, const u16* __restrict__ pos_w2,
    const float* __restrict__ bns, float* __restrict__ out_x,
    u32* __restrict__ done, u16* __restrict__ Xw, int g, int lane){
  const int q = lane >> 4, l15 = lane & 15;
  const int gc0 = g * 32;
  const int b = gc0 >> 11, s0 = gc0 & 2047;
  for (;;){
    u32 d = (lane < 32)
      ? __hip_atomic_load(done + gc0 + lane, __ATOMIC_RELAXED, __HIP_MEMORY_SCOPE_AGENT)
      : 1u;
    if (__all(d != 0)) break;
    __builtin_amdgcn_s_sleep(16);
  }
  __builtin_amdgcn_fence(__ATOMIC_ACQUIRE, "agent");
  #pragma unroll
  for (int it = 0; it < 8; ++it){
    int lidx = it*64 + lane;
    int col = lidx >> 4, kq = lidx & 15;
    uint4 v = *(const uint4*)(x_mid + (size_t)(gc0 + col)*COUT + kq*8);
    *(uint4*)(Xw + col*LDSPAD + kq*8) = v;
  }
  __syncthreads();
  u32 resid[8][2][2];
  #pragma unroll
  for (int mt = 0; mt < 8; ++mt)
    #pragma unroll
    for (int nt = 0; nt < 2; ++nt){
      uint2 rr = *(const uint2*)(Xw + (nt*16 + l15)*LDSPAD + mt*16 + q*4);
      resid[mt][nt][0] = rr.x; resid[mt][nt][1] = rr.y;
    }
  f32x4 acc[8][2];
  res_block(pos_w1,             pos_w2,             bns + 1280, bns + 1536, Xw, q, l15, resid, acc, true);
  res_block(pos_w1 + COUT*COUT, pos_w2 + COUT*COUT, bns + 1792, bns + 2048, Xw, q, l15, resid, acc, false);
  #pragma unroll
  for (int mt = 0; mt < 8; ++mt)
    #pragma unroll
    for (int nt = 0; nt < 2; ++nt)
      #pragma unroll
      for (int r = 0; r < 4; ++r){
        int row = mt*16 + q*4 + r;
        int colx = s0 + nt*16 + l15;
        out_x[(size_t)(b*COUT + row)*NS + colx] = acc[mt][nt][r];
      }
}

// ---------------------------------------------------------------------------
#define GRID_FPS    B_                 // 8
#define GRID_KM     (B_*NS/8)          // 2048 blocks x 8 waves = 16384 centers
#define GRID_POS    (B_*NS/K_/8)       // 64 blocks x 8 waves = 512 groups

__global__ __launch_bounds__(512) void mega_kernel(
    const float* __restrict__ xyz, const float* __restrict__ feat,
    const u16* __restrict__ te_w, const u16* __restrict__ pre_w1, const u16* __restrict__ pre_w2,
    const u16* __restrict__ pos_w1, const u16* __restrict__ pos_w2,
    const float* __restrict__ bns, int* __restrict__ fps_idx,
    u16* __restrict__ x_mid, u32* __restrict__ done,
    float* __restrict__ out_xyz, float* __restrict__ out_x){
  __shared__ ShAll sh;
  const int bid = blockIdx.x;
  const int t = threadIdx.x;
  const int wid = t >> 6, lane = t & 63;
  if (bid < GRID_FPS){
    fps_path(xyz, fps_idx, sh.f, bid, t);
  } else if (bid < GRID_FPS + GRID_KM){
    // INTERLEAVED mapping: consumer i covers batch i%8, offset (i/8)*8 ->
    // the resident fleet tracks ALL 8 fps streams concurrently (no
    // batch-0-only residency serialization).
    const int i = bid - GRID_FPS;
    const int g0 = (i & 7) * NS + (i >> 3) * 8;
    // block gate: ONE scalar poller -> minimal L3 spin traffic; per-wave
    // verify loops (above) provide the actual correctness guarantee.
    if (t == 0){
      while (__hip_atomic_load(fps_idx + g0 + 7, __ATOMIC_RELAXED,
                               __HIP_MEMORY_SCOPE_AGENT) < 0)
        __builtin_amdgcn_s_sleep(16);
    }
    __syncthreads();
    knnmid_path(xyz, feat, te_w, pre_w1, pre_w2, bns, fps_idx, x_mid, done, out_xyz,
                sh.m.X[wid], sh.m.scr[wid], g0 + wid, lane);
  } else {
    const int idx = (bid - GRID_FPS - GRID_KM)*8 + wid;   // 0..511
    const int g = (idx & 7) * (NS/K_) + (idx >> 3);       // interleave batches
    pos_path(x_mid, pos_w1, pos_w2, bns, out_x, done, sh.p.X[wid], g, lane);
  }
}

// ---------------------------------------------------------------------------
extern "C" void kernel_launch(void* const* d_in, const int* in_sizes, int n_in,
                              void* d_out, int out_size, void* d_ws, size_t ws_size,
                              hipStream_t stream){
  (void)in_sizes; (void)n_in; (void)out_size; (void)ws_size;
  const float* xyz    = (const float*)d_in[0];
  const float* feat   = (const float*)d_in[1];

  // ws layout (16B aligned, ~4.7 MB total):
  char* ws = (char*)d_ws;
  float* bns     = (float*)ws;                          // 16 KiB (9.2 used)
  u16*   wbf     = (u16*)(ws + 16384);                  // 288 KiB bf16 weights
  int*   fps_idx = (int*)(ws + 16384 + 294912);         // 64 KiB
  u32*   done    = (u32*)(ws + 16384 + 294912 + 65536); // 64 KiB
  u16*   x_mid   = (u16*)(ws + 16384 + 294912 + 65536 + 65536); // 4 MiB
  float* out_xyz = (float*)d_out;                       // (8,2048,3) f32
  float* out_x   = (float*)d_out + B_*NS*3;             // (8,128,2048) f32

  // bf16 weight staging: te(16384) pre_w1(32768) pre_w2(32768) pos_w1(32768) pos_w2(32768)
  u16* te_w   = wbf;
  u16* pre_w1 = wbf + 16384;
  u16* pre_w2 = wbf + 49152;
  u16* pos_w1 = wbf + 81920;
  u16* pos_w2 = wbf + 114688;
  wcvt_kernel<<<64,  256, 0, stream>>>((const float*)d_in[2],  te_w,   16384);
  wcvt_kernel<<<128, 256, 0, stream>>>((const float*)d_in[7],  pre_w1, 32768);
  wcvt_kernel<<<128, 256, 0, stream>>>((const float*)d_in[8],  pre_w2, 32768);
  wcvt_kernel<<<128, 256, 0, stream>>>((const float*)d_in[17], pos_w1, 32768);
  wcvt_kernel<<<128, 256, 0, stream>>>((const float*)d_in[18], pos_w2, 32768);
  clear_kernel<<<64, 256, 0, stream>>>(fps_idx, done);

  // dict order: te_g/b/m/v = 3..6 ; pre: w1,w2,g1,g2,b1,b2,m1,m2,v1,v2 = 7..16 ; pos = 17..26
  BnPtrs bp;
  const int gi[9] = {3, 9, 10, 9, 10, 19, 20, 19, 20};
  const int bbi[9]= {4, 11,12, 11,12, 21, 22, 21, 22};
  const int mi[9] = {5, 13,14, 13,14, 23, 24, 23, 24};
  const int vi[9] = {6, 15,16, 15,16, 25, 26, 25, 26};
  const int of[9] = {0, 0, 0, 128,128, 0, 0, 128,128};
  for (int k = 0; k < 9; ++k){
    bp.g[k] = (const float*)d_in[gi[k]]  + of[k];
    bp.b[k] = (const float*)d_in[bbi[k]] + of[k];
    bp.m[k] = (const float*)d_in[mi[k]]  + of[k];
    bp.v[k] = (const float*)d_in[vi[k]]  + of[k];
  }

  bn_pre_kernel<<<9, 128, 0, stream>>>(bp, bns);
  mega_kernel<<<GRID_FPS + GRID_KM + GRID_POS, 512, 0, stream>>>(
      xyz, feat, te_w, pre_w1, pre_w2, pos_w1, pos_w2, bns,
      fps_idx, x_mid, done, out_xyz, out_x);
}